// Round 6
// baseline (6902.959 us; speedup 1.0000x reference)
//
#include <hip/hip_runtime.h>
#include <stdint.h>

// Problem dims
#define Tn 512
#define Bn 128
#define NTOK (Bn*Tn)     // 65536
#define En 300
#define Hn 300
#define On 9
#define LDK 328          // LDS row stride in shorts (656 B rows, 16B-aligned)
#define HS 60            // hidden units per slice
#define NSL 5            // slices per direction (5*60 = 300)
#define NCH 8            // batch chunks
#define NPAIR 4          // chunk pairs per direction (2 chunks share a block)
#define MC 16            // batch rows per chunk (one m-tile)
#define GLD 244          // padded Gsm row stride (floats): 4*240%32==0 was a 4-way write conflict
#define NBLK (2*NPAIR*NSL) // 40 blocks, 2 streams each
#define NTHR 960         // 15 waves = 1 m-tile x 15 n-tiles; == MC*HS cell threads

#define HXW 304          // g_hx row stride in dwords (one tagged packet per hidden unit)
#define HXSLOT (Bn*HXW)  // dwords per parity slot
#define HXDIR (2*HXSLOT) // dwords per direction (2 parity slots)

typedef short s4v __attribute__((ext_vector_type(4)));
typedef short s8v __attribute__((ext_vector_type(8)));
typedef float f4v __attribute__((ext_vector_type(4)));

// ---- static device scratch (d_ws unused) ----
__device__ unsigned short g_hcat[NTOK * 2 * Hn];   // 78,643,200 B — h outputs
// Tagged h-exchange packets: dword = (bf16(h) << 16) | produced_step.
// The data IS the flag. Publishes MUST stay agent-scope atomics (partial-line
// plain stores in non-coherent XCD L2s would false-share on writeback).
__device__ unsigned int   g_hx[2 * HXDIR];         // 622,592 B

__device__ inline float b2f(unsigned short u){ unsigned v = ((unsigned)u) << 16; float f; __builtin_memcpy(&f, &v, 4); return f; }
__device__ inline unsigned short f2b(float f){ unsigned u; __builtin_memcpy(&u, &f, 4); u = u + 0x7fffu + ((u >> 16) & 1u); return (unsigned short)(u >> 16); }
__device__ inline float sigf(float x){ return 1.f / (1.f + __expf(-x)); }
__device__ inline float tanh_f(float x){ return 2.f / (1.f + __expf(-2.f * x)) - 1.f; }

// LDS-only barrier: drains lgkmcnt but NOT vmcnt, so in-flight global stores
// (the fire-and-forget h/hcat publishes) never sit on the critical path.
__device__ inline void bar_lgkm(){ asm volatile("s_waitcnt lgkmcnt(0)\n\ts_barrier" ::: "memory"); }

// ---------------- K0: init h-exchange tags to 0xFFFF (never matches a real step) ----------------
__global__ __launch_bounds__(256) void k_zero()
{
    const int i = blockIdx.x * 256 + threadIdx.x;
    const int stride = gridDim.x * 256;
    for (int j = i; j < 2 * HXDIR; j += stride) g_hx[j] = 0xFFFFu;
}

// ---------------- K1: fused bidirectional LSTM recurrence, 2 streams/block ----------------
// R6: each block advances TWO independent same-direction chunks (streams A,B).
// The agent-scope exchange latency of both streams is paid in ONE shared
// window per iteration (polls issued together after MFMA1 — the R4-proven
// placement; R5 showed atomics issued before MFMA1 do NOT pipeline).
// Weights/biases are stream-invariant (same dir) — no extra weight registers.
// LDS: Aemb single-buffered (safe: writeback after barC3 > all MFMA1 reads
// which end before barB) + shared Gsm with staggered dump/cell => 57.6 KB.
__global__ __launch_bounds__(NTHR, 2) void k_lstm(
    const int* __restrict__ x, const float* __restrict__ emb,
    const float* __restrict__ W_ih_f, const float* __restrict__ W_hh_f, const float* __restrict__ b_f,
    const float* __restrict__ W_ih_b, const float* __restrict__ W_hh_b, const float* __restrict__ b_b)
{
    const int bi    = blockIdx.x;
    const int dir   = bi / (NPAIR * NSL);
    const int rem   = bi % (NPAIR * NSL);
    const int pair  = rem / NSL;
    const int slice = rem % NSL;
    const int j0    = slice * HS;
    const int b0A   = (2 * pair)     * MC;
    const int b0B   = (2 * pair + 1) * MC;

    const float* Wih  = dir ? W_ih_b : W_ih_f;
    const float* Whh  = dir ? W_hh_b : W_hh_f;
    const float* bias = dir ? b_b    : b_f;
    unsigned int* hxd = g_hx + dir * HXDIR;

    __shared__ __align__(16) unsigned short AembA[MC * LDK];   // 10.5 KB (single-buffered)
    __shared__ __align__(16) unsigned short AembB[MC * LDK];   // 10.5 KB
    __shared__ __align__(16) unsigned short HbA[MC * LDK];     // 10.5 KB
    __shared__ __align__(16) unsigned short HbB[MC * LDK];     // 10.5 KB
    __shared__ __align__(16) float Gsm[MC * GLD];              // 15.6 KB, time-shared A->B

    const int tid  = threadIdx.x;
    const int lane = tid & 63;
    const int wid  = tid >> 6;              // 15 waves
    const int n0   = wid * 16;              // 15 n-tiles (240 gate cols); single m-tile
    const int kq   = (lane >> 4) * 8;       // k-subgroup within 32

    // ---- preload weight B-fragments (fp32 -> bf16 once, weight-stationary) ----
    // local gate col layout: [i(60) | f(60) | g(60) | o(60)]
    const int nloc = n0 + (lane & 15);      // 0..239
    const int q    = nloc / HS;             // gate index 0..3
    const int jjn  = nloc % HS;
    const int grow = q * Hn + j0 + jjn;     // global row in [1200]
    s8v bih[10], bhh[10];
#pragma unroll
    for (int kc = 0; kc < 10; kc++) {
        int kb = kc * 32 + kq;
        s8v fi = {0,0,0,0,0,0,0,0}, fh = {0,0,0,0,0,0,0,0};
#pragma unroll
        for (int j = 0; j < 8; j++) {
            int k = kb + j;
            if (k < En) {
                fi[j] = (short)f2b(Wih[grow * En + k]);
                fh[j] = (short)f2b(Whh[grow * Hn + k]);
            }
        }
        bih[kc] = fi; bhh[kc] = fh;
    }

    // ---- per-thread cell state: tid <-> (batch row ebl, unit ejj); NTHR == MC*HS ----
    const int ebl = tid / HS;   // 0..15
    const int ejj = tid % HS;   // 0..59
    const float bi_i = bias[0 * Hn + j0 + ejj];
    const float bi_f = bias[1 * Hn + j0 + ejj];
    const float bi_g = bias[2 * Hn + j0 + ejj];
    const float bi_o = bias[3 * Hn + j0 + ejj];
    float cregA = 0.f, cregB = 0.f;
    const bool pub = ((ejj & 1) == 0);      // even-ejj lanes store packed hcat dwords

    // ---- P3 assignment: 4 packets per thread over the OTHER 4 slices ----
    // (MC * 4*HS == 4*NTHR exactly; own slice [j0,j0+60) comes via LDS self-write)
    int goffA[4], goffB[4], loff[4];
#pragma unroll
    for (int j = 0; j < 4; j++) {
        int i  = tid + j * NTHR;            // 0..3839
        int r  = i / (4 * HS);              // row 0..15
        int c2 = i - r * (4 * HS);          // 0..239
        int c  = (c2 < j0) ? c2 : (c2 + HS);// skip own slice's 60 columns
        goffA[j] = (b0A + r) * HXW + c;
        goffB[j] = (b0B + r) * HXW + c;
        loff[j]  = r * LDK + c;
    }

    // ---- prologue: stage emb(s=0) for both streams; zero Hb pads ----
    {
        const int t0 = dir ? (Tn - 1) : 0;
        for (int i = tid; i < MC * 80; i += NTHR) {
            int r = i / 80, c = i - r * 80;
            s4v vA = {0,0,0,0}, vB = {0,0,0,0};
            if (c < 75) {
                int xiA = x[(b0A + r) * Tn + t0];
                int xiB = x[(b0B + r) * Tn + t0];
                float4 fA = *(const float4*)(emb + (size_t)xiA * En + c * 4);
                float4 fB = *(const float4*)(emb + (size_t)xiB * En + c * 4);
                vA[0] = (short)f2b(fA.x); vA[1] = (short)f2b(fA.y);
                vA[2] = (short)f2b(fA.z); vA[3] = (short)f2b(fA.w);
                vB[0] = (short)f2b(fB.x); vB[1] = (short)f2b(fB.y);
                vB[2] = (short)f2b(fB.z); vB[3] = (short)f2b(fB.w);
            }
            *(s4v*)&AembA[r * LDK + c * 4] = vA;
            *(s4v*)&AembB[r * LDK + c * 4] = vB;
        }
        // MFMA2 reads shorts [0,320) per row; only [0,300) is ever filled. Zero
        // the pad once (garbage could be NaN; NaN*0 = NaN poisons the MFMA).
        if (tid < MC * 20) {
            int r = tid / 20, c = 300 + (tid % 20);
            HbA[r * LDK + c] = 0;
            HbB[r * LDK + c] = 0;
        }
        __syncthreads();
    }

#pragma unroll 1
    for (int s = 0; s < Tn; s++) {
        const int t = dir ? (Tn - 1 - s) : s;

        // early token loads for s+1 (PLAIN loads — these pipeline; R5 showed
        // atomics here do not). Waits sink to first use in the pf gather.
        int xtA[2], xtB[2];
        const bool do_pf = (s + 1 < Tn);
        if (do_pf) {
            const int tn1 = dir ? (Tn - 2 - s) : (s + 1);
#pragma unroll
            for (int k = 0; k < 2; k++) {
                int i = tid + k * NTHR;
                if (i < MC * 80) {
                    int r = i / 80;
                    xtA[k] = x[(b0A + r) * Tn + tn1];
                    xtB[k] = x[(b0B + r) * Tn + tn1];
                }
            }
        }

        // MFMA1: input projection for both streams (no global deps)
        f4v accA = {0.f,0.f,0.f,0.f}, accB = {0.f,0.f,0.f,0.f};
        {
            const unsigned short* aA = &AembA[(lane & 15) * LDK + kq];
            const unsigned short* aB = &AembB[(lane & 15) * LDK + kq];
#pragma unroll
            for (int kc = 0; kc < 10; kc++) {
                accA = __builtin_amdgcn_mfma_f32_16x16x32_bf16(*(const s8v*)(aA + kc * 32), bih[kc], accA, 0, 0, 0);
                accB = __builtin_amdgcn_mfma_f32_16x16x32_bf16(*(const s8v*)(aB + kc * 32), bih[kc], accB, 0, 0, 0);
            }
        }

        if (s) {
            // P3: both streams' polls share ONE latency window. Issue B's 4
            // loads, then A's 4; check A (retry), then B (already landed).
            // Reload-all retry is safe by the parity-slot induction.
            const unsigned tgt = (unsigned)(s - 1);
            const unsigned int* hsrc = hxd + (s & 1) * HXSLOT;
            unsigned int pb0, pb1, pb2, pb3, pa0, pa1, pa2, pa3;
            pb0 = __hip_atomic_load(hsrc + goffB[0], __ATOMIC_RELAXED, __HIP_MEMORY_SCOPE_AGENT);
            pb1 = __hip_atomic_load(hsrc + goffB[1], __ATOMIC_RELAXED, __HIP_MEMORY_SCOPE_AGENT);
            pb2 = __hip_atomic_load(hsrc + goffB[2], __ATOMIC_RELAXED, __HIP_MEMORY_SCOPE_AGENT);
            pb3 = __hip_atomic_load(hsrc + goffB[3], __ATOMIC_RELAXED, __HIP_MEMORY_SCOPE_AGENT);
            pa0 = __hip_atomic_load(hsrc + goffA[0], __ATOMIC_RELAXED, __HIP_MEMORY_SCOPE_AGENT);
            pa1 = __hip_atomic_load(hsrc + goffA[1], __ATOMIC_RELAXED, __HIP_MEMORY_SCOPE_AGENT);
            pa2 = __hip_atomic_load(hsrc + goffA[2], __ATOMIC_RELAXED, __HIP_MEMORY_SCOPE_AGENT);
            pa3 = __hip_atomic_load(hsrc + goffA[3], __ATOMIC_RELAXED, __HIP_MEMORY_SCOPE_AGENT);
            for (;;) {
                unsigned bad = ((pa0 ^ tgt) | (pa1 ^ tgt) | (pa2 ^ tgt) | (pa3 ^ tgt)) & 0xffffu;
                if (!bad) break;
                pa0 = __hip_atomic_load(hsrc + goffA[0], __ATOMIC_RELAXED, __HIP_MEMORY_SCOPE_AGENT);
                pa1 = __hip_atomic_load(hsrc + goffA[1], __ATOMIC_RELAXED, __HIP_MEMORY_SCOPE_AGENT);
                pa2 = __hip_atomic_load(hsrc + goffA[2], __ATOMIC_RELAXED, __HIP_MEMORY_SCOPE_AGENT);
                pa3 = __hip_atomic_load(hsrc + goffA[3], __ATOMIC_RELAXED, __HIP_MEMORY_SCOPE_AGENT);
            }
            for (;;) {
                unsigned bad = ((pb0 ^ tgt) | (pb1 ^ tgt) | (pb2 ^ tgt) | (pb3 ^ tgt)) & 0xffffu;
                if (!bad) break;
                pb0 = __hip_atomic_load(hsrc + goffB[0], __ATOMIC_RELAXED, __HIP_MEMORY_SCOPE_AGENT);
                pb1 = __hip_atomic_load(hsrc + goffB[1], __ATOMIC_RELAXED, __HIP_MEMORY_SCOPE_AGENT);
                pb2 = __hip_atomic_load(hsrc + goffB[2], __ATOMIC_RELAXED, __HIP_MEMORY_SCOPE_AGENT);
                pb3 = __hip_atomic_load(hsrc + goffB[3], __ATOMIC_RELAXED, __HIP_MEMORY_SCOPE_AGENT);
            }
            HbA[loff[0]] = (unsigned short)(pa0 >> 16);
            HbA[loff[1]] = (unsigned short)(pa1 >> 16);
            HbA[loff[2]] = (unsigned short)(pa2 >> 16);
            HbA[loff[3]] = (unsigned short)(pa3 >> 16);
            HbB[loff[0]] = (unsigned short)(pb0 >> 16);
            HbB[loff[1]] = (unsigned short)(pb1 >> 16);
            HbB[loff[2]] = (unsigned short)(pb2 >> 16);
            HbB[loff[3]] = (unsigned short)(pb3 >> 16);
        }

        // emb gathers for s+1 (after polls — never ahead of them in the
        // in-order vmcnt queue); latency hides under MFMA2 + dumps + cells.
        float4 pfA[2], pfB[2];
        if (do_pf) {
#pragma unroll
            for (int k = 0; k < 2; k++) {
                int i = tid + k * NTHR;
                if (i < MC * 80) {
                    int r = i / 80, c = i - r * 80;
                    if (c < 75) {
                        pfA[k] = *(const float4*)(emb + (size_t)xtA[k] * En + c * 4);
                        pfB[k] = *(const float4*)(emb + (size_t)xtB[k] * En + c * 4);
                    }
                }
            }
        }

        if (s) {
            bar_lgkm();   // bar B: HbA/HbB ready (LDS only — no vmcnt drain)

            // MFMA2: recurrent part for both streams
            const unsigned short* hA = &HbA[(lane & 15) * LDK + kq];
            const unsigned short* hB = &HbB[(lane & 15) * LDK + kq];
#pragma unroll
            for (int kc = 0; kc < 10; kc++) {
                accA = __builtin_amdgcn_mfma_f32_16x16x32_bf16(*(const s8v*)(hA + kc * 32), bhh[kc], accA, 0, 0, 0);
                accB = __builtin_amdgcn_mfma_f32_16x16x32_bf16(*(const s8v*)(hB + kc * 32), bhh[kc], accB, 0, 0, 0);
            }
        }
        // s == 0: h_0 == 0 — skip P3/MFMA2.

        const int col   = n0 + (lane & 15);
        const int rbase = (lane >> 4) * 4;

        // ---- stream A tail: dump -> cell -> publish ----
#pragma unroll
        for (int r2 = 0; r2 < 4; r2++) Gsm[(rbase + r2) * GLD + col] = accA[r2];
        bar_lgkm();   // bar C1: Gsm(A) ready
        {
            float gi  = Gsm[ebl * GLD + 0 * HS + ejj] + bi_i;
            float gf  = Gsm[ebl * GLD + 1 * HS + ejj] + bi_f;
            float gg2 = Gsm[ebl * GLD + 2 * HS + ejj] + bi_g;
            float go  = Gsm[ebl * GLD + 3 * HS + ejj] + bi_o;
            float iv = sigf(gi), fv = sigf(gf), gv = tanh_f(gg2), ov = sigf(go);
            cregA = fv * cregA + iv * gv;
            float h = ov * tanh_f(cregA);
            unsigned hb16 = (unsigned)f2b(h);
            HbA[ebl * LDK + j0 + ejj] = (unsigned short)hb16;   // own slice via LDS
            __hip_atomic_store(hxd + ((s + 1) & 1) * HXSLOT + (b0A + ebl) * HXW + (j0 + ejj),
                               (hb16 << 16) | (unsigned)s,
                               __ATOMIC_RELAXED, __HIP_MEMORY_SCOPE_AGENT);
            float hn = __shfl_down(h, 1);
            if (pub) {
                unsigned pkt = hb16 | ((unsigned)f2b(hn) << 16);
                __hip_atomic_store((unsigned int*)g_hcat
                                       + (((size_t)((b0A + ebl) * Tn + t)) * (2 * Hn) + dir * Hn + j0 + ejj) / 2,
                                   pkt, __ATOMIC_RELAXED, __HIP_MEMORY_SCOPE_AGENT);
            }
        }
        bar_lgkm();   // bar C2: all Gsm(A) reads done — safe to overwrite

        // ---- stream B tail ----
#pragma unroll
        for (int r2 = 0; r2 < 4; r2++) Gsm[(rbase + r2) * GLD + col] = accB[r2];
        bar_lgkm();   // bar C3: Gsm(B) ready
        {
            float gi  = Gsm[ebl * GLD + 0 * HS + ejj] + bi_i;
            float gf  = Gsm[ebl * GLD + 1 * HS + ejj] + bi_f;
            float gg2 = Gsm[ebl * GLD + 2 * HS + ejj] + bi_g;
            float go  = Gsm[ebl * GLD + 3 * HS + ejj] + bi_o;
            float iv = sigf(gi), fv = sigf(gf), gv = tanh_f(gg2), ov = sigf(go);
            cregB = fv * cregB + iv * gv;
            float h = ov * tanh_f(cregB);
            unsigned hb16 = (unsigned)f2b(h);
            HbB[ebl * LDK + j0 + ejj] = (unsigned short)hb16;
            __hip_atomic_store(hxd + ((s + 1) & 1) * HXSLOT + (b0B + ebl) * HXW + (j0 + ejj),
                               (hb16 << 16) | (unsigned)s,
                               __ATOMIC_RELAXED, __HIP_MEMORY_SCOPE_AGENT);
            float hn = __shfl_down(h, 1);
            if (pub) {
                unsigned pkt = hb16 | ((unsigned)f2b(hn) << 16);
                __hip_atomic_store((unsigned int*)g_hcat
                                       + (((size_t)((b0B + ebl) * Tn + t)) * (2 * Hn) + dir * Hn + j0 + ejj) / 2,
                                   pkt, __ATOMIC_RELAXED, __HIP_MEMORY_SCOPE_AGENT);
            }
        }

        // writeback prefetched emb(s+1) (all MFMA1 reads of Aemb ended before
        // bar B < bar C3, so single-buffered overwrite is safe here)
        if (do_pf) {
#pragma unroll
            for (int k = 0; k < 2; k++) {
                int i = tid + k * NTHR;
                if (i < MC * 80) {
                    int r = i / 80, c = i - r * 80;
                    s4v vA = {0,0,0,0}, vB = {0,0,0,0};
                    if (c < 75) {
                        vA[0] = (short)f2b(pfA[k].x); vA[1] = (short)f2b(pfA[k].y);
                        vA[2] = (short)f2b(pfA[k].z); vA[3] = (short)f2b(pfA[k].w);
                        vB[0] = (short)f2b(pfB[k].x); vB[1] = (short)f2b(pfB[k].y);
                        vB[2] = (short)f2b(pfB[k].z); vB[3] = (short)f2b(pfB[k].w);
                    }
                    *(s4v*)&AembA[r * LDK + c * 4] = vA;
                    *(s4v*)&AembB[r * LDK + c * 4] = vB;
                }
            }
        }
        bar_lgkm();   // bar D: Aemb writebacks + Hb self-writes + Gsm(B) reads done
    }
}

// ---------------- K2: fused out-projection + softmax, one wave per 16 positions ----------------
__global__ __launch_bounds__(256) void k_out(
    const float* __restrict__ W_lin, const float* __restrict__ b_lin, float* __restrict__ out)
{
    __shared__ float Wl[On * 2 * Hn];  // 21.6 KB
    __shared__ float bl[On];
    const int tid = threadIdx.x;
    for (int i = tid; i < On * 2 * Hn; i += 256) Wl[i] = W_lin[i];
    if (tid < On) bl[tid] = b_lin[tid];
    __syncthreads();

    const int lane = tid & 63;
    const int w    = tid >> 6;
    const int wg   = blockIdx.x * 4 + w;      // 4096 waves
    for (int it = 0; it < 16; it++) {
        const int p = wg * 16 + it;           // 0..65535
        const unsigned int* rowd = (const unsigned int*)(g_hcat + (size_t)p * (2 * Hn)); // 300 dwords
        float part[On];
#pragma unroll
        for (int o = 0; o < On; o++) part[o] = 0.f;
#pragma unroll
        for (int c = 0; c < 5; c++) {
            int k = lane + 64 * c;            // dword index, 2 shorts each
            if (k < Hn) {
                unsigned v2 = rowd[k];
                float vlo = b2f((unsigned short)(v2 & 0xffffu));
                float vhi = b2f((unsigned short)(v2 >> 16));
#pragma unroll
                for (int o = 0; o < On; o++)
                    part[o] += vlo * Wl[o * (2 * Hn) + 2 * k] + vhi * Wl[o * (2 * Hn) + 2 * k + 1];
            }
        }
#pragma unroll
        for (int off = 32; off >= 1; off >>= 1) {
#pragma unroll
            for (int o = 0; o < On; o++) part[o] += __shfl_xor(part[o], off, 64);
        }
        if (lane == 0) {
            float lg[On];
            float m = -1e30f;
#pragma unroll
            for (int o = 0; o < On; o++) { lg[o] = part[o] + bl[o]; m = fmaxf(m, lg[o]); }
            float ssum = 0.f;
#pragma unroll
            for (int o = 0; o < On; o++) { lg[o] = __expf(lg[o] - m); ssum += lg[o]; }
            float inv = 1.f / ssum;
#pragma unroll
            for (int o = 0; o < On; o++) out[(size_t)p * On + o] = lg[o] * inv;
        }
    }
}

// ---------------- host launcher ----------------
extern "C" void kernel_launch(void* const* d_in, const int* in_sizes, int n_in,
                              void* d_out, int out_size, void* d_ws, size_t ws_size,
                              hipStream_t stream)
{
    (void)in_sizes; (void)n_in; (void)out_size; (void)d_ws; (void)ws_size;
    const int* x = (const int*)d_in[0];
    const float* emb   = (const float*)d_in[1];
    const float* Wih_f = (const float*)d_in[2];
    const float* Whh_f = (const float*)d_in[3];
    const float* bf    = (const float*)d_in[4];
    const float* Wih_b = (const float*)d_in[5];
    const float* Whh_b = (const float*)d_in[6];
    const float* bb    = (const float*)d_in[7];
    const float* Wlin  = (const float*)d_in[8];
    const float* blin  = (const float*)d_in[9];
    float* out = (float*)d_out;

    k_zero<<<128, 256, 0, stream>>>();

    void* args[] = {
        (void*)&x, (void*)&emb,
        (void*)&Wih_f, (void*)&Whh_f, (void*)&bf,
        (void*)&Wih_b, (void*)&Whh_b, (void*)&bb
    };
    hipLaunchCooperativeKernel((const void*)k_lstm, dim3(NBLK), dim3(NTHR), args, 0, stream);

    k_out<<<1024, 256, 0, stream>>>(Wlin, blin, out);
}

// Round 8
// 2176.076 us; speedup vs baseline: 3.1722x; 3.1722x over previous
//
#include <hip/hip_runtime.h>
#include <stdint.h>

// Problem dims
#define Tn 512
#define Bn 128
#define NTOK (Bn*Tn)     // 65536
#define En 300
#define Hn 300
#define On 9
#define LDK 328          // LDS row stride in shorts (656 B rows, 16B-aligned)
#define HS 60            // hidden units per slice
#define NSL 5            // slices per direction (5*60 = 300)
#define NCH 8            // batch chunks
#define MC 16            // batch rows per chunk (one m-tile)
#define NBLK (2*NCH*NSL) // 80 blocks
#define NTHR 960         // 15 waves = 1 m-tile x 15 n-tiles; == MC*HS cell threads

#define HXWQ 152         // g_hx row stride in QWORDS (one qword = 2 units + tag)
#define HXSLOTQ (Bn*HXWQ)  // qwords per parity slot
#define HXDIRQ (2*HXSLOTQ) // qwords per direction (2 parity slots)

typedef short s4v __attribute__((ext_vector_type(4)));
typedef short s8v __attribute__((ext_vector_type(8)));
typedef float f4v __attribute__((ext_vector_type(4)));

// ---- static device scratch (d_ws unused) ----
__device__ unsigned short g_hcat[NTOK * 2 * Hn];   // 78,643,200 B — h outputs
// Tagged h-exchange packets, QWORD: high 32 = 2x bf16 (units 2u,2u+1),
// low 32 = produced_step. One 8B atomic publishes data+validity together.
// Publishes MUST stay agent-scope atomics (partial-line plain stores in
// non-coherent XCD L2s would false-share on full-line writeback).
__device__ unsigned long long g_hx[2 * HXDIRQ];    // 622,592 B

__device__ inline float b2f(unsigned short u){ unsigned v = ((unsigned)u) << 16; float f; __builtin_memcpy(&f, &v, 4); return f; }
__device__ inline unsigned short f2b(float f){ unsigned u; __builtin_memcpy(&u, &f, 4); u = u + 0x7fffu + ((u >> 16) & 1u); return (unsigned short)(u >> 16); }
__device__ inline float sigf(float x){ return 1.f / (1.f + __expf(-x)); }
__device__ inline float tanh_f(float x){ return 2.f / (1.f + __expf(-2.f * x)) - 1.f; }

// LDS-only barrier: drains lgkmcnt but NOT vmcnt, so in-flight global stores
// (the fire-and-forget h/hcat publishes) never sit on the critical path.
__device__ inline void bar_lgkm(){ asm volatile("s_waitcnt lgkmcnt(0)\n\ts_barrier" ::: "memory"); }

// ---------------- K0: init h-exchange tags (low dword never matches a real step) ----------------
__global__ __launch_bounds__(256) void k_zero()
{
    const int i = blockIdx.x * 256 + threadIdx.x;
    const int stride = gridDim.x * 256;
    for (int j = i; j < 2 * HXDIRQ; j += stride) g_hx[j] = 0xFFFFFFFFFFFFFFFFull;
}

// ---------------- K1: fused bidirectional LSTM recurrence ----------------
// R8 == R7 resubmitted (R7 never ran: GPU acquisition timeout).
// R7 = R4 skeleton (best verified) + two serial-chain cuts:
//  (1) GATE-INTERLEAVED COLUMNS + IN-WAVE CELL: local gate col = 4*unit+gate,
//      so each 4-lane group's C fragment holds all 4 gates of one (row,unit).
//      An 8x shfl_xor 4x4 transpose replaces the Gsm dump + barrier + read
//      (~600cy + bank conflicts) on the publish path. Gsm deleted; 2 barriers
//      per step instead of 3; publish happens right after MFMA2.
//  (2) QWORD PACKETS: (2 bf16 units | 32b tag) per 8B atomic. Poll fan-in
//      2 qwords/thread (was 4 dwords); publish store count halves.
__global__ __launch_bounds__(NTHR, 4) void k_lstm(
    const int* __restrict__ x, const float* __restrict__ emb,
    const float* __restrict__ W_ih_f, const float* __restrict__ W_hh_f, const float* __restrict__ b_f,
    const float* __restrict__ W_ih_b, const float* __restrict__ W_hh_b, const float* __restrict__ b_b)
{
    const int bi    = blockIdx.x;
    const int dir   = bi / (NCH * NSL);
    const int rem   = bi % (NCH * NSL);
    const int chunk = rem / NSL;
    const int slice = rem % NSL;
    const int j0    = slice * HS;
    const int b0    = chunk * MC;

    const float* Wih  = dir ? W_ih_b : W_ih_f;
    const float* Whh  = dir ? W_hh_b : W_hh_f;
    const float* bias = dir ? b_b    : b_f;
    unsigned long long* hxq = g_hx + (size_t)dir * HXDIRQ;

    __shared__ __align__(16) unsigned short Aemb[2][MC * LDK]; // 21 KB emb staging, double-buffered
    __shared__ __align__(16) unsigned short Hb[MC * LDK];      // 10.5 KB h staging
    __shared__ unsigned short Xl[MC * Tn];                     // 16 KB token ids (vocab<65536)

    const int tid  = threadIdx.x;
    const int lane = tid & 63;
    const int wid  = tid >> 6;              // 15 waves
    const int n0   = wid * 16;              // 15 n-tiles (240 gate cols); single m-tile
    const int kq   = (lane >> 4) * 8;       // k-subgroup within 32

    // ---- preload weight B-fragments (fp32 -> bf16 once, weight-stationary) ----
    // GATE-INTERLEAVED local col layout: nloc = 4*unit + gate (unit 0..59)
    const int nloc = n0 + (lane & 15);      // 0..239
    const int gq   = nloc & 3;              // gate index 0..3 (i,f,g,o)
    const int uq   = nloc >> 2;             // unit within slice 0..59
    const int grow = gq * Hn + j0 + uq;     // global row in [1200]
    s8v bih[10], bhh[10];
#pragma unroll
    for (int kc = 0; kc < 10; kc++) {
        int kb = kc * 32 + kq;
        s8v fi = {0,0,0,0,0,0,0,0}, fh = {0,0,0,0,0,0,0,0};
#pragma unroll
        for (int j = 0; j < 8; j++) {
            int k = kb + j;
            if (k < En) {
                fi[j] = (short)f2b(Wih[grow * En + k]);
                fh[j] = (short)f2b(Whh[grow * Hn + k]);
            }
        }
        bih[kc] = fi; bhh[kc] = fh;
    }

    // ---- per-LANE cell assignment (from the C-fragment layout + 4x4 transpose):
    // lane owns cell (batch row crow, unit cj); every lane of every wave active.
    const int crow = 4 * (lane >> 4) + (lane & 3);  // 0..15
    const int cu   = (lane >> 2) & 3;               // unit-in-wave 0..3
    const int cj   = j0 + 4 * wid + cu;             // unit within direction slice range
    const float bi_i = bias[0 * Hn + cj];
    const float bi_f = bias[1 * Hn + cj];
    const float bi_g = bias[2 * Hn + cj];
    const float bi_o = bias[3 * Hn + cj];
    float creg = 0.f;
    const bool pub = ((cu & 1) == 0);               // even units publish the pair (cj, cj+1)

    // ---- P3 assignment: 2 qword packets per thread over the OTHER 4 slices ----
    // (MC * 4*HS/2 == 1920 == 2*NTHR exactly; own slice comes via LDS self-write)
    int goffA[2], loffA[2];
#pragma unroll
    for (int jj = 0; jj < 2; jj++) {
        int i  = tid + jj * NTHR;            // 0..1919
        int r  = i / 120;                    // row 0..15  (120 qwords of other slices)
        int cq = i - r * 120;                // 0..119
        int c  = 2 * cq;                     // unit pair base 0..238
        c = (c < j0) ? c : (c + HS);         // skip own slice's 60 units (HS even)
        goffA[jj] = (b0 + r) * HXWQ + (c >> 1);
        loffA[jj] = (r * LDK + c) >> 1;      // dword index into Hb
    }

    // ---- prologue: stage emb(s=0) into Aemb[0]; stage token ids; zero Hb pad ----
    {
        const int t0 = dir ? (Tn - 1) : 0;
        for (int i = tid; i < MC * 80; i += NTHR) {
            int r = i / 80, c = i - r * 80;
            s4v v = {0, 0, 0, 0};
            if (c < 75) {
                int xi = x[(b0 + r) * Tn + t0];
                float4 f = *(const float4*)(emb + (size_t)xi * En + c * 4);
                v[0] = (short)f2b(f.x); v[1] = (short)f2b(f.y);
                v[2] = (short)f2b(f.z); v[3] = (short)f2b(f.w);
            }
            *(s4v*)&Aemb[0][r * LDK + c * 4] = v;
        }
        for (int i = tid; i < MC * Tn; i += NTHR) {
            int r = i >> 9, tt = i & (Tn - 1);
            Xl[i] = (unsigned short)x[(b0 + r) * Tn + tt];  // Xl[r*512 + t]
        }
        // MFMA2 reads shorts [0,320) per row; only [0,300) is ever filled. Zero
        // the pad once (garbage could be NaN; NaN*0 = NaN poisons the MFMA).
        if (tid < MC * 20) {
            int r = tid / 20, c = 300 + (tid % 20);
            Hb[r * LDK + c] = 0;
        }
        __syncthreads();
    }

#pragma unroll 1
    for (int s = 0; s < Tn; s++) {
        const int t   = dir ? (Tn - 1 - s) : s;
        const int cur = s & 1, nxt = cur ^ 1;

        // MFMA1: input projection part from Aemb[cur] (runs during the wait window)
        f4v acc = {0.f, 0.f, 0.f, 0.f};
        {
            const unsigned short* abase = &Aemb[cur][(lane & 15) * LDK + kq];
#pragma unroll
            for (int kc = 0; kc < 10; kc++) {
                s8v a = *(const s8v*)(abase + kc * 32);
                acc = __builtin_amdgcn_mfma_f32_16x16x32_bf16(a, bih[kc], acc, 0, 0, 0);
            }
        }

        if (s) {
            // P3: poll 2 qword packets (detect == load, one hop). Unconditional
            // straight-line loads; reload-all retry is safe by the parity-slot
            // induction (satisfied packets can't change until WE publish s).
            const unsigned tgt = (unsigned)(s - 1);
            const unsigned long long* hsrc = hxq + (size_t)(s & 1) * HXSLOTQ;
            unsigned long long p0, p1;
            p0 = __hip_atomic_load(hsrc + goffA[0], __ATOMIC_RELAXED, __HIP_MEMORY_SCOPE_AGENT);
            p1 = __hip_atomic_load(hsrc + goffA[1], __ATOMIC_RELAXED, __HIP_MEMORY_SCOPE_AGENT);
            for (;;) {
                if (((unsigned)p0 == tgt) & ((unsigned)p1 == tgt)) break;
                p0 = __hip_atomic_load(hsrc + goffA[0], __ATOMIC_RELAXED, __HIP_MEMORY_SCOPE_AGENT);
                p1 = __hip_atomic_load(hsrc + goffA[1], __ATOMIC_RELAXED, __HIP_MEMORY_SCOPE_AGENT);
            }
            ((unsigned int*)Hb)[loffA[0]] = (unsigned int)(p0 >> 32);
            ((unsigned int*)Hb)[loffA[1]] = (unsigned int)(p1 >> 32);
        }

        // emb prefetch for s+1 (token ids from LDS): issued after the poll so it
        // never sits ahead of poll loads in the in-order vmcnt queue; its HBM
        // latency hides under MFMA2 + cell.
        float4 pf[2];
        const bool do_pf = (s + 1 < Tn);
        if (do_pf) {
            const int tn1 = dir ? (Tn - 2 - s) : (s + 1);
#pragma unroll
            for (int k = 0; k < 2; k++) {
                int i = tid + k * NTHR;            // < 1920; valid when < 1280 = MC*80
                if (i < MC * 80) {
                    int r = i / 80, c = i - r * 80;
                    if (c < 75) {
                        int xi = (int)Xl[(r << 9) + tn1];
                        pf[k] = *(const float4*)(emb + (size_t)xi * En + c * 4);
                    }
                }
            }
        }

        if (s) {
            bar_lgkm();   // bar B: Hb ready (LDS only — no vmcnt drain)

            // MFMA2: recurrent part from Hb
            const unsigned short* abase = &Hb[(lane & 15) * LDK + kq];
#pragma unroll
            for (int kc = 0; kc < 10; kc++) {
                s8v a = *(const s8v*)(abase + kc * 32);
                acc = __builtin_amdgcn_mfma_f32_16x16x32_bf16(a, bhh[kc], acc, 0, 0, 0);
            }
        }
        // s == 0: h_0 == 0, recurrent term is zero — skip P3/MFMA2 entirely.

        // ---- in-wave 4x4 transpose within each 4-lane group (quad-perm shfls):
        // M[p][e] = acc[e] of lane p = gate_p(row rbase+e); result: lane p holds
        // all 4 gates of row rbase+p. Verified mapping: c[p][e] = M[e][p].
        float vi, vf2, vg, vo;
        {
            const bool q0 = (lane & 1) != 0;
            const bool q1 = (lane & 2) != 0;
            float a0 = acc[0], a1 = acc[1], a2 = acc[2], a3 = acc[3];
            float s0 = __shfl_xor(a1, 1), s1 = __shfl_xor(a0, 1);
            float s2 = __shfl_xor(a3, 1), s3 = __shfl_xor(a2, 1);
            float b0v = q0 ? s0 : a0;
            float b1v = q0 ? a1 : s1;
            float b2v = q0 ? s2 : a2;
            float b3v = q0 ? a3 : s3;
            s0 = __shfl_xor(b2v, 2); s1 = __shfl_xor(b3v, 2);
            s2 = __shfl_xor(b0v, 2); s3 = __shfl_xor(b1v, 2);
            vi  = q1 ? s0 : b0v;
            vf2 = q1 ? s1 : b1v;
            vg  = q1 ? b2v : s2;
            vo  = q1 ? b3v : s3;
        }

        // elementwise LSTM cell + publishes (no LDS round trip, no barrier)
        {
            float gi  = vi  + bi_i;
            float gf  = vf2 + bi_f;
            float gg2 = vg  + bi_g;
            float go  = vo  + bi_o;
            float ivv = sigf(gi), fv = sigf(gf), gv = tanh_f(gg2), ov = sigf(go);
            creg = fv * creg + ivv * gv;
            float h = ov * tanh_f(creg);
            unsigned hb16 = (unsigned)f2b(h);
            float hn = __shfl_down(h, 4);          // partner unit cj+1 (lane+4, same row)
            if (pub) {
                unsigned pkt = hb16 | ((unsigned)f2b(hn) << 16);
                // own-slice h for step s+1 via LDS (bar D orders it)
                ((unsigned int*)Hb)[(crow * LDK + cj) >> 1] = pkt;
                // tagged qword packet for the other 4 slices (fire-and-forget)
                __hip_atomic_store(hxq + (size_t)((s + 1) & 1) * HXSLOTQ + (b0 + crow) * HXWQ + (cj >> 1),
                                   ((unsigned long long)pkt << 32) | (unsigned long long)(unsigned)s,
                                   __ATOMIC_RELAXED, __HIP_MEMORY_SCOPE_AGENT);
                // hcat output
                __hip_atomic_store((unsigned int*)g_hcat
                                       + (((size_t)((b0 + crow) * Tn + t)) * (2 * Hn) + dir * Hn + cj) / 2,
                                   pkt, __ATOMIC_RELAXED, __HIP_MEMORY_SCOPE_AGENT);
            }
        }

        // writeback prefetched emb(s+1) -> Aemb[nxt] (covered by bar D)
        if (do_pf) {
#pragma unroll
            for (int k = 0; k < 2; k++) {
                int i = tid + k * NTHR;
                if (i < MC * 80) {
                    int r = i / 80, c = i - r * 80;
                    s4v v = {0, 0, 0, 0};
                    if (c < 75) {
                        v[0] = (short)f2b(pf[k].x); v[1] = (short)f2b(pf[k].y);
                        v[2] = (short)f2b(pf[k].z); v[3] = (short)f2b(pf[k].w);
                    }
                    *(s4v*)&Aemb[nxt][r * LDK + c * 4] = v;
                }
            }
        }
        bar_lgkm();   // bar D: Aemb[nxt] + Hb self-writes visible (LDS only)
    }
}

// ---------------- K2: fused out-projection + softmax, one wave per 16 positions ----------------
__global__ __launch_bounds__(256) void k_out(
    const float* __restrict__ W_lin, const float* __restrict__ b_lin, float* __restrict__ out)
{
    __shared__ float Wl[On * 2 * Hn];  // 21.6 KB
    __shared__ float bl[On];
    const int tid = threadIdx.x;
    for (int i = tid; i < On * 2 * Hn; i += 256) Wl[i] = W_lin[i];
    if (tid < On) bl[tid] = b_lin[tid];
    __syncthreads();

    const int lane = tid & 63;
    const int w    = tid >> 6;
    const int wg   = blockIdx.x * 4 + w;      // 4096 waves
    for (int it = 0; it < 16; it++) {
        const int p = wg * 16 + it;           // 0..65535
        const unsigned int* rowd = (const unsigned int*)(g_hcat + (size_t)p * (2 * Hn)); // 300 dwords
        float part[On];
#pragma unroll
        for (int o = 0; o < On; o++) part[o] = 0.f;
#pragma unroll
        for (int c = 0; c < 5; c++) {
            int k = lane + 64 * c;            // dword index, 2 shorts each
            if (k < Hn) {
                unsigned v2 = rowd[k];
                float vlo = b2f((unsigned short)(v2 & 0xffffu));
                float vhi = b2f((unsigned short)(v2 >> 16));
#pragma unroll
                for (int o = 0; o < On; o++)
                    part[o] += vlo * Wl[o * (2 * Hn) + 2 * k] + vhi * Wl[o * (2 * Hn) + 2 * k + 1];
            }
        }
#pragma unroll
        for (int off = 32; off >= 1; off >>= 1) {
#pragma unroll
            for (int o = 0; o < On; o++) part[o] += __shfl_xor(part[o], off, 64);
        }
        if (lane == 0) {
            float lg[On];
            float m = -1e30f;
#pragma unroll
            for (int o = 0; o < On; o++) { lg[o] = part[o] + bl[o]; m = fmaxf(m, lg[o]); }
            float ssum = 0.f;
#pragma unroll
            for (int o = 0; o < On; o++) { lg[o] = __expf(lg[o] - m); ssum += lg[o]; }
            float inv = 1.f / ssum;
#pragma unroll
            for (int o = 0; o < On; o++) out[(size_t)p * On + o] = lg[o] * inv;
        }
    }
}

// ---------------- host launcher ----------------
extern "C" void kernel_launch(void* const* d_in, const int* in_sizes, int n_in,
                              void* d_out, int out_size, void* d_ws, size_t ws_size,
                              hipStream_t stream)
{
    (void)in_sizes; (void)n_in; (void)out_size; (void)d_ws; (void)ws_size;
    const int* x = (const int*)d_in[0];
    const float* emb   = (const float*)d_in[1];
    const float* Wih_f = (const float*)d_in[2];
    const float* Whh_f = (const float*)d_in[3];
    const float* bf    = (const float*)d_in[4];
    const float* Wih_b = (const float*)d_in[5];
    const float* Whh_b = (const float*)d_in[6];
    const float* bb    = (const float*)d_in[7];
    const float* Wlin  = (const float*)d_in[8];
    const float* blin  = (const float*)d_in[9];
    float* out = (float*)d_out;

    k_zero<<<128, 256, 0, stream>>>();

    void* args[] = {
        (void*)&x, (void*)&emb,
        (void*)&Wih_f, (void*)&Whh_f, (void*)&bf,
        (void*)&Wih_b, (void*)&Whh_b, (void*)&bb
    };
    hipLaunchCooperativeKernel((const void*)k_lstm, dim3(NBLK), dim3(NTHR), args, 0, stream);

    k_out<<<1024, 256, 0, stream>>>(Wlin, blin, out);
}